// Round 1
// baseline (1340.644 us; speedup 1.0000x reference)
//
#include <hip/hip_runtime.h>
#include <math.h>

#define N_PROP 1024
#define C_FEAT 32
#define ROI 7
#define SR 6
#define S_GRID 42
#define IMG_H 360
#define IMG_W 1200
#define BEV_H 700
#define BEV_W 800
#define D_FEAT (C_FEAT*ROI*ROI)   // 1568
#define HID 2048
#define NMS_K 100
#define NMS_THR 0.01f

// ---------------- workspace layout (float offsets) ----------------
#define WS_IMG_BOXES 0
#define WS_BEV_BOXES (WS_IMG_BOXES + 4*N_PROP)
#define WS_FUSED     (WS_BEV_BOXES + 4*N_PROP)
#define WS_H1        (WS_FUSED + N_PROP*D_FEAT)
#define WS_H2        (WS_H1 + N_PROP*HID)
#define WS_OBJS      (WS_H2 + N_PROP*HID)
#define WS_OFF       (WS_OBJS + 2*N_PROP)
#define WS_ORIENT    (WS_OFF + 10*N_PROP)
#define WS_PRED      (WS_ORIENT + N_PROP)
#define WS_PBEV      (WS_PRED + 6*N_PROP)
#define WS_SCORES    (WS_PBEV + 4*N_PROP)
#define WS_IDX       (WS_SCORES + N_PROP)   // ints

// ---------------- K1: project boxes ----------------
__global__ void boxes_kernel(const float* __restrict__ anchors,
                             const float* __restrict__ calib,
                             const int* __restrict__ imshape,
                             float* __restrict__ img_boxes,
                             float* __restrict__ bev_boxes) {
    int n = blockIdx.x * blockDim.x + threadIdx.x;
    if (n >= N_PROP) return;
    float x = anchors[n*6+0], y = anchors[n*6+1], z = anchors[n*6+2];
    float dx = anchors[n*6+3], dy = anchors[n*6+4], dz = anchors[n*6+5];

    // BEV: X_MIN=-40, Z_MAX=70, VOX=0.1
    bev_boxes[n*4+0] = ((x - dx*0.5f) - (-40.0f)) / 0.1f;
    bev_boxes[n*4+1] = (70.0f - (z + dz*0.5f)) / 0.1f;
    bev_boxes[n*4+2] = ((x + dx*0.5f) - (-40.0f)) / 0.1f;
    bev_boxes[n*4+3] = (70.0f - (z - dz*0.5f)) / 0.1f;

    float P[12];
    #pragma unroll
    for (int i = 0; i < 12; i++) P[i] = calib[i];

    float umin = 1e30f, vmin = 1e30f, umax = -1e30f, vmax = -1e30f;
    #pragma unroll
    for (int k = 0; k < 8; k++) {
        float fsx = (k & 4) ? 1.0f : -1.0f;
        float fsy = (k & 2) ? 1.0f : -1.0f;
        float fsz = (k & 1) ? 1.0f : -1.0f;
        float cx = x + fsx * dx * 0.5f;
        float cy = y + fsy * dy * 0.5f;
        float cz = z + fsz * dz * 0.5f;
        float p0 = P[0]*cx + P[1]*cy + P[2]*cz + P[3];
        float p1 = P[4]*cx + P[5]*cy + P[6]*cz + P[7];
        float p2 = P[8]*cx + P[9]*cy + P[10]*cz + P[11];
        float zz = fmaxf(p2, 0.1f);
        float u = p0 / zz, v = p1 / zz;
        umin = fminf(umin, u); umax = fmaxf(umax, u);
        vmin = fminf(vmin, v); vmax = fmaxf(vmax, v);
    }
    float Hf = (float)imshape[0];
    float Wf = (float)imshape[1];
    img_boxes[n*4+0] = fminf(fmaxf(umin, 0.0f), Wf);
    img_boxes[n*4+1] = fminf(fmaxf(vmin, 0.0f), Hf);
    img_boxes[n*4+2] = fminf(fmaxf(umax, 0.0f), Wf);
    img_boxes[n*4+3] = fminf(fmaxf(vmax, 0.0f), Hf);
}

// ---------------- K2: roi_align both maps + fuse ----------------
__global__ __launch_bounds__(256) void roi_fuse_kernel(
        const float* __restrict__ imgF, const float* __restrict__ bevF,
        const float* __restrict__ img_boxes, const float* __restrict__ bev_boxes,
        const float* __restrict__ img_mask, const float* __restrict__ bev_mask,
        float* __restrict__ fused) {
    int b = blockIdx.x;
    __shared__ float s_w[2][2][S_GRID];     // [map][axis 0=x,1=y][j]
    __shared__ int   s_i0[2][2][S_GRID], s_i1[2][2][S_GRID];
    __shared__ float s_box[2][4];
    int tid = threadIdx.x;
    if (tid < 4) s_box[0][tid] = img_boxes[b*4+tid];
    else if (tid < 8) s_box[1][tid-4] = bev_boxes[b*4+tid-4];
    __syncthreads();
    for (int t = tid; t < 2*2*S_GRID; t += blockDim.x) {
        int m = t / (2*S_GRID);
        int axis = (t / S_GRID) % 2;
        int j = t % S_GRID;
        float lo = s_box[m][axis];
        float hi = s_box[m][axis+2];
        int dim = (axis == 0) ? (m == 0 ? IMG_W : BEV_W) : (m == 0 ? IMG_H : BEV_H);
        float c1 = lo - 0.5f, c2 = hi - 0.5f;
        float g = ((float)j + 0.5f) / (float)S_GRID;
        float xs = c1 + g * (c2 - c1);
        float x0f = floorf(xs);
        x0f = fminf(fmaxf(x0f, 0.0f), (float)(dim-1));
        float w = fminf(fmaxf(xs - x0f, 0.0f), 1.0f);
        int i0 = (int)x0f;
        int i1 = min(i0 + 1, dim - 1);
        s_w[m][axis][j] = w;
        s_i0[m][axis][j] = i0;
        s_i1[m][axis][j] = i1;
    }
    __syncthreads();
    float m0 = img_mask[0], m1 = bev_mask[0];
    float scale = 1.0f / ((m0 + m1) * 36.0f);

    for (int o = tid; o < D_FEAT; o += blockDim.x) {
        int c = o / 49;
        int r = o % 49;
        int py = r / 7, px = r % 7;
        float acc = 0.0f;
        // map 0: img
        {
            const float* f = imgF + c * (IMG_H * IMG_W);
            float s = 0.0f;
            #pragma unroll
            for (int sy = 0; sy < SR; sy++) {
                int yi = py * SR + sy;
                int y0 = s_i0[0][1][yi], y1 = s_i1[0][1][yi];
                float wy = s_w[0][1][yi];
                const float* r0 = f + y0 * IMG_W;
                const float* r1 = f + y1 * IMG_W;
                #pragma unroll
                for (int sx = 0; sx < SR; sx++) {
                    int xi = px * SR + sx;
                    int x0 = s_i0[0][0][xi], x1 = s_i1[0][0][xi];
                    float wx = s_w[0][0][xi];
                    float v00 = r0[x0], v01 = r0[x1], v10 = r1[x0], v11 = r1[x1];
                    s += v00*(1.0f-wy)*(1.0f-wx) + v01*(1.0f-wy)*wx
                       + v10*wy*(1.0f-wx) + v11*wy*wx;
                }
            }
            acc += m0 * s;
        }
        // map 1: bev
        {
            const float* f = bevF + c * (BEV_H * BEV_W);
            float s = 0.0f;
            #pragma unroll
            for (int sy = 0; sy < SR; sy++) {
                int yi = py * SR + sy;
                int y0 = s_i0[1][1][yi], y1 = s_i1[1][1][yi];
                float wy = s_w[1][1][yi];
                const float* r0 = f + y0 * BEV_W;
                const float* r1 = f + y1 * BEV_W;
                #pragma unroll
                for (int sx = 0; sx < SR; sx++) {
                    int xi = px * SR + sx;
                    int x0 = s_i0[1][0][xi], x1 = s_i1[1][0][xi];
                    float wx = s_w[1][0][xi];
                    float v00 = r0[x0], v01 = r0[x1], v10 = r1[x0], v11 = r1[x1];
                    s += v00*(1.0f-wy)*(1.0f-wx) + v01*(1.0f-wy)*wx
                       + v10*wy*(1.0f-wx) + v11*wy*wx;
                }
            }
            acc += m1 * s;
        }
        fused[b * D_FEAT + o] = acc * scale;
    }
}

// ---------------- K3/K4: fp32 tiled GEMM, C = relu(A@B + bias) ----------------
#define GBM 64
#define GBN 64
#define GBK 16
__global__ __launch_bounds__(256) void gemm_relu_kernel(
        const float* __restrict__ A, const float* __restrict__ B,
        const float* __restrict__ bias, float* __restrict__ C,
        int M, int N, int K, int do_relu) {
    __shared__ float As[GBK][GBM + 4];
    __shared__ float Bs[GBK][GBN];
    int tid = threadIdx.x;
    int tx = tid & 15, ty = tid >> 4;
    int m0 = blockIdx.y * GBM, n0 = blockIdx.x * GBN;
    float acc[4][4] = {};
    int arow = tid >> 2;                // 0..63
    int acg  = (tid & 3) << 2;          // 0,4,8,12
    int brow = tid >> 4;                // 0..15
    int bcol = (tid & 15) << 2;         // 0..60

    for (int k0 = 0; k0 < K; k0 += GBK) {
        float4 av = *(const float4*)(A + (size_t)(m0 + arow) * K + k0 + acg);
        float4 bv = *(const float4*)(B + (size_t)(k0 + brow) * N + n0 + bcol);
        __syncthreads();
        As[acg+0][arow] = av.x;
        As[acg+1][arow] = av.y;
        As[acg+2][arow] = av.z;
        As[acg+3][arow] = av.w;
        *(float4*)&Bs[brow][bcol] = bv;
        __syncthreads();
        #pragma unroll
        for (int kk = 0; kk < GBK; kk++) {
            float4 a = *(const float4*)&As[kk][ty * 4];
            float4 b = *(const float4*)&Bs[kk][tx * 4];
            float aa[4] = {a.x, a.y, a.z, a.w};
            float bb[4] = {b.x, b.y, b.z, b.w};
            #pragma unroll
            for (int i = 0; i < 4; i++)
                #pragma unroll
                for (int j = 0; j < 4; j++)
                    acc[i][j] += aa[i] * bb[j];
        }
    }
    float4 bv = *(const float4*)(bias + n0 + tx * 4);
    float bb[4] = {bv.x, bv.y, bv.z, bv.w};
    #pragma unroll
    for (int i = 0; i < 4; i++) {
        int m = m0 + ty * 4 + i;
        float4 o;
        float v0 = acc[i][0] + bb[0];
        float v1 = acc[i][1] + bb[1];
        float v2 = acc[i][2] + bb[2];
        float v3 = acc[i][3] + bb[3];
        if (do_relu) {
            v0 = fmaxf(v0, 0.0f); v1 = fmaxf(v1, 0.0f);
            v2 = fmaxf(v2, 0.0f); v3 = fmaxf(v3, 0.0f);
        }
        o.x = v0; o.y = v1; o.z = v2; o.w = v3;
        *(float4*)(C + (size_t)m * N + n0 + tx * 4) = o;
    }
}

// ---------------- K5: heads (obj/off/ang) + postprocess per row ----------------
__global__ __launch_bounds__(256) void heads_kernel(
        const float* __restrict__ h,
        const float* __restrict__ Wc, const float* __restrict__ bc,
        const float* __restrict__ Wo, const float* __restrict__ bo,
        const float* __restrict__ Wa, const float* __restrict__ ba,
        const float* __restrict__ anchors,
        float* __restrict__ obj_soft, float* __restrict__ off_out,
        float* __restrict__ orient, float* __restrict__ pred,
        float* __restrict__ pbev, float* __restrict__ scores) {
    int row = blockIdx.x;
    const float* hr = h + (size_t)row * HID;
    float acc[14];
    #pragma unroll
    for (int j = 0; j < 14; j++) acc[j] = 0.0f;
    for (int k = threadIdx.x; k < HID; k += 256) {
        float hv = hr[k];
        acc[0]  += hv * Wc[k*2+0];
        acc[1]  += hv * Wc[k*2+1];
        #pragma unroll
        for (int j = 0; j < 10; j++) acc[2+j] += hv * Wo[k*10+j];
        acc[12] += hv * Wa[k*2+0];
        acc[13] += hv * Wa[k*2+1];
    }
    #pragma unroll
    for (int d = 32; d > 0; d >>= 1) {
        #pragma unroll
        for (int j = 0; j < 14; j++) acc[j] += __shfl_down(acc[j], d);
    }
    __shared__ float red[4][14];
    int wid = threadIdx.x >> 6, lane = threadIdx.x & 63;
    if (lane == 0) {
        #pragma unroll
        for (int j = 0; j < 14; j++) red[wid][j] = acc[j];
    }
    __syncthreads();
    if (threadIdx.x == 0) {
        float f[14];
        #pragma unroll
        for (int j = 0; j < 14; j++)
            f[j] = red[0][j] + red[1][j] + red[2][j] + red[3][j];
        float obj0 = f[0] + bc[0], obj1 = f[1] + bc[1];
        float offv[10];
        #pragma unroll
        for (int j = 0; j < 10; j++) offv[j] = f[2+j] + bo[j];
        float ang0 = f[12] + ba[0], ang1 = f[13] + ba[1];
        float mx = fmaxf(obj0, obj1);
        float e0 = expf(obj0 - mx), e1 = expf(obj1 - mx);
        float den = e0 + e1;
        obj_soft[row*2+0] = e0 / den;
        obj_soft[row*2+1] = e1 / den;
        scores[row] = obj1;
        orient[row] = atan2f(ang1, ang0);
        float pa[6];
        #pragma unroll
        for (int j = 0; j < 6; j++) {
            pa[j] = anchors[row*6+j] + offv[j];
            pred[row*6+j] = pa[j];
        }
        #pragma unroll
        for (int j = 0; j < 10; j++) off_out[row*10+j] = offv[j];
        float x = pa[0], z = pa[2], ddx = pa[3], ddz = pa[5];
        pbev[row*4+0] = ((x - ddx*0.5f) - (-40.0f)) / 0.1f;
        pbev[row*4+1] = (70.0f - (z + ddz*0.5f)) / 0.1f;
        pbev[row*4+2] = ((x + ddx*0.5f) - (-40.0f)) / 0.1f;
        pbev[row*4+3] = (70.0f - (z - ddz*0.5f)) / 0.1f;
    }
}

// ---------------- K6: sequential NMS, single wave ----------------
__global__ void nms_kernel(const float* __restrict__ boxes,
                           const float* __restrict__ scores_g,
                           int* __restrict__ idx_out) {
    __shared__ float sb[N_PROP][4];
    __shared__ float sa[N_PROP];
    int lane = threadIdx.x;   // 64 threads
    float sc[16], x1[16], y1[16], x2[16], y2[16], ar[16];
    #pragma unroll
    for (int j = 0; j < 16; j++) {
        int g = lane + 64*j;
        float b0 = boxes[g*4+0], b1 = boxes[g*4+1];
        float b2 = boxes[g*4+2], b3 = boxes[g*4+3];
        x1[j] = b0; y1[j] = b1; x2[j] = b2; y2[j] = b3;
        ar[j] = (b2 - b0) * (b3 - b1);
        sc[j] = scores_g[g];
        sb[g][0] = b0; sb[g][1] = b1; sb[g][2] = b2; sb[g][3] = b3;
        sa[g] = ar[j];
    }
    for (int t = 0; t < NMS_K; t++) {
        float bv = -INFINITY;
        int bi = 0x7fffffff;
        #pragma unroll
        for (int j = 0; j < 16; j++) {
            int g = lane + 64*j;
            if (sc[j] > bv || (sc[j] == bv && g < bi)) { bv = sc[j]; bi = g; }
        }
        #pragma unroll
        for (int d = 1; d < 64; d <<= 1) {
            float ov = __shfl_xor(bv, d);
            int   oi = __shfl_xor(bi, d);
            if (ov > bv || (ov == bv && oi < bi)) { bv = ov; bi = oi; }
        }
        if (lane == 0) idx_out[t] = bi;
        float px1 = sb[bi][0], py1 = sb[bi][1], px2 = sb[bi][2], py2 = sb[bi][3];
        float pa = sa[bi];
        #pragma unroll
        for (int j = 0; j < 16; j++) {
            int g = lane + 64*j;
            float xx1 = fmaxf(x1[j], px1), yy1 = fmaxf(y1[j], py1);
            float xx2 = fminf(x2[j], px2), yy2 = fminf(y2[j], py2);
            float inter = fmaxf(xx2 - xx1, 0.0f) * fmaxf(yy2 - yy1, 0.0f);
            float iou = inter / (ar[j] + pa - inter + 1e-6f);
            if (iou > NMS_THR || g == bi) sc[j] = -INFINITY;
        }
    }
}

// ---------------- K7: gather outputs ----------------
__global__ void gather_kernel(const int* __restrict__ idx,
                              const float* __restrict__ obj_soft,
                              const float* __restrict__ pred,
                              const float* __restrict__ off,
                              const float* __restrict__ orient,
                              float* __restrict__ out) {
    int i = threadIdx.x;
    if (i < NMS_K) {
        int j = idx[i];
        out[2*i+0] = obj_soft[j*2+0];
        out[2*i+1] = obj_soft[j*2+1];
        #pragma unroll
        for (int t = 0; t < 6; t++) out[200 + 6*i + t] = pred[j*6+t];
        #pragma unroll
        for (int t = 0; t < 10; t++) out[800 + 10*i + t] = off[j*10+t];
        #pragma unroll
        for (int t = 0; t < 6; t++) out[1800 + 7*i + t] = pred[j*6+t];
        out[1800 + 7*i + 6] = 0.0f;
        out[2500 + i] = orient[j];
    }
}

extern "C" void kernel_launch(void* const* d_in, const int* in_sizes, int n_in,
                              void* d_out, int out_size, void* d_ws, size_t ws_size,
                              hipStream_t stream) {
    const float* imgF     = (const float*)d_in[0];
    const float* bevF     = (const float*)d_in[1];
    const float* anchors  = (const float*)d_in[2];
    const float* calib    = (const float*)d_in[3];
    // d_in[4] ground_plane: multiplied by 0.0 in reference — unused
    const float* img_mask = (const float*)d_in[5];
    const float* bev_mask = (const float*)d_in[6];
    const float* W1 = (const float*)d_in[7];
    const float* b1 = (const float*)d_in[8];
    const float* W2 = (const float*)d_in[9];
    const float* b2 = (const float*)d_in[10];
    const float* Wc = (const float*)d_in[11];
    const float* bc = (const float*)d_in[12];
    const float* Wo = (const float*)d_in[13];
    const float* bo = (const float*)d_in[14];
    const float* Wa = (const float*)d_in[15];
    const float* ba = (const float*)d_in[16];
    const int* image_shape = (const int*)d_in[17];

    float* ws = (float*)d_ws;
    float* img_boxes = ws + WS_IMG_BOXES;
    float* bev_boxes = ws + WS_BEV_BOXES;
    float* fused     = ws + WS_FUSED;
    float* h1        = ws + WS_H1;
    float* h2        = ws + WS_H2;
    float* obj_soft  = ws + WS_OBJS;
    float* off       = ws + WS_OFF;
    float* orient    = ws + WS_ORIENT;
    float* pred      = ws + WS_PRED;
    float* pbev      = ws + WS_PBEV;
    float* scores    = ws + WS_SCORES;
    int*   idx       = (int*)(ws + WS_IDX);

    boxes_kernel<<<N_PROP/64, 64, 0, stream>>>(anchors, calib, image_shape,
                                               img_boxes, bev_boxes);
    roi_fuse_kernel<<<N_PROP, 256, 0, stream>>>(imgF, bevF, img_boxes, bev_boxes,
                                                img_mask, bev_mask, fused);
    gemm_relu_kernel<<<dim3(HID/GBN, N_PROP/GBM), 256, 0, stream>>>(
        fused, W1, b1, h1, N_PROP, HID, D_FEAT, 1);
    gemm_relu_kernel<<<dim3(HID/GBN, N_PROP/GBM), 256, 0, stream>>>(
        h1, W2, b2, h2, N_PROP, HID, HID, 1);
    heads_kernel<<<N_PROP, 256, 0, stream>>>(h2, Wc, bc, Wo, bo, Wa, ba, anchors,
                                             obj_soft, off, orient, pred, pbev, scores);
    nms_kernel<<<1, 64, 0, stream>>>(pbev, scores, idx);
    gather_kernel<<<1, 128, 0, stream>>>(idx, obj_soft, pred, off, orient,
                                         (float*)d_out);
}

// Round 2
// 835.543 us; speedup vs baseline: 1.6045x; 1.6045x over previous
//
#include <hip/hip_runtime.h>
#include <math.h>

#define N_PROP 1024
#define C_FEAT 32
#define ROI 7
#define SR 6
#define S_GRID 42
#define IMG_H 360
#define IMG_W 1200
#define BEV_H 700
#define BEV_W 800
#define D_FEAT (C_FEAT*ROI*ROI)   // 1568
#define HID 2048
#define NMS_K 100
#define NMS_THR 0.01f

// ---------------- workspace layout (float offsets) ----------------
// img_s/bev_s are dead after GEMM1; h2 overlaps them.
#define WS_IMG_BOXES 0
#define WS_BEV_BOXES (WS_IMG_BOXES + 4*N_PROP)
#define WS_IMG_S     (WS_BEV_BOXES + 4*N_PROP)               // 1024*1568
#define WS_BEV_S     (WS_IMG_S + N_PROP*D_FEAT)              // 1024*1568
#define WS_H2        WS_IMG_S                                 // overlaps img_s+bev_s (2.10M < 3.21M)
#define WS_H1        (WS_BEV_S + N_PROP*D_FEAT)              // 1024*2048
#define WS_OBJS      (WS_H1 + N_PROP*HID)
#define WS_OFF       (WS_OBJS + 2*N_PROP)
#define WS_ORIENT    (WS_OFF + 10*N_PROP)
#define WS_PRED      (WS_ORIENT + N_PROP)
#define WS_PBEV      (WS_PRED + 6*N_PROP)
#define WS_SCORES    (WS_PBEV + 4*N_PROP)
#define WS_IDX       (WS_SCORES + N_PROP)   // ints

// ---------------- K1: project boxes ----------------
__global__ void boxes_kernel(const float* __restrict__ anchors,
                             const float* __restrict__ calib,
                             const int* __restrict__ imshape,
                             float* __restrict__ img_boxes,
                             float* __restrict__ bev_boxes) {
    int n = blockIdx.x * blockDim.x + threadIdx.x;
    if (n >= N_PROP) return;
    float x = anchors[n*6+0], y = anchors[n*6+1], z = anchors[n*6+2];
    float dx = anchors[n*6+3], dy = anchors[n*6+4], dz = anchors[n*6+5];

    bev_boxes[n*4+0] = ((x - dx*0.5f) - (-40.0f)) / 0.1f;
    bev_boxes[n*4+1] = (70.0f - (z + dz*0.5f)) / 0.1f;
    bev_boxes[n*4+2] = ((x + dx*0.5f) - (-40.0f)) / 0.1f;
    bev_boxes[n*4+3] = (70.0f - (z - dz*0.5f)) / 0.1f;

    float P[12];
    #pragma unroll
    for (int i = 0; i < 12; i++) P[i] = calib[i];

    float umin = 1e30f, vmin = 1e30f, umax = -1e30f, vmax = -1e30f;
    #pragma unroll
    for (int k = 0; k < 8; k++) {
        float fsx = (k & 4) ? 1.0f : -1.0f;
        float fsy = (k & 2) ? 1.0f : -1.0f;
        float fsz = (k & 1) ? 1.0f : -1.0f;
        float cx = x + fsx * dx * 0.5f;
        float cy = y + fsy * dy * 0.5f;
        float cz = z + fsz * dz * 0.5f;
        float p0 = P[0]*cx + P[1]*cy + P[2]*cz + P[3];
        float p1 = P[4]*cx + P[5]*cy + P[6]*cz + P[7];
        float p2 = P[8]*cx + P[9]*cy + P[10]*cz + P[11];
        float zz = fmaxf(p2, 0.1f);
        float u = p0 / zz, v = p1 / zz;
        umin = fminf(umin, u); umax = fmaxf(umax, u);
        vmin = fminf(vmin, v); vmax = fmaxf(vmax, v);
    }
    float Hf = (float)imshape[0];
    float Wf = (float)imshape[1];
    img_boxes[n*4+0] = fminf(fmaxf(umin, 0.0f), Wf);
    img_boxes[n*4+1] = fminf(fmaxf(vmin, 0.0f), Hf);
    img_boxes[n*4+2] = fminf(fmaxf(umax, 0.0f), Wf);
    img_boxes[n*4+3] = fminf(fmaxf(vmax, 0.0f), Hf);
}

// ---------------- K2: roi_align, one wave per (channel, box, map) ----------------
// lane = grid-x index (42 active). Sorted gather addresses within the wave ->
// HW coalescer merges same-cache-line lanes (bev box span ~160B = ~3 lines/load).
// Writes RAW 36-sample sums (no mask, no /36) -> combined in GEMM1 A-staging.
__global__ __launch_bounds__(64) void roi_map_kernel(
        const float* __restrict__ imgF, const float* __restrict__ bevF,
        const float* __restrict__ img_boxes, const float* __restrict__ bev_boxes,
        float* __restrict__ img_out, float* __restrict__ bev_out) {
    int c = blockIdx.x;      // channel 0..31
    int b = blockIdx.y;      // box 0..1023
    int mapid = blockIdx.z;  // 0=img, 1=bev

    const float* F; const float* boxes; float* outp; int W, H;
    if (mapid == 0) { F = imgF; boxes = img_boxes; outp = img_out; W = IMG_W; H = IMG_H; }
    else            { F = bevF; boxes = bev_boxes; outp = bev_out; W = BEV_W; H = BEV_H; }
    const float* f = F + (size_t)c * W * H;

    int lane = threadIdx.x;
    float bx1 = boxes[b*4+0], by1 = boxes[b*4+1];
    float bx2 = boxes[b*4+2], by2 = boxes[b*4+3];

    __shared__ int   s_iy0[S_GRID], s_iy1[S_GRID];
    __shared__ float s_wy[S_GRID];
    __shared__ float s_out[49];

    // per-lane x params (registers), per-row y params (LDS)
    int x0i = 0, x1i = 0;
    float wx = 0.0f;
    if (lane < S_GRID) {
        float g = ((float)lane + 0.5f) / (float)S_GRID;
        float c1 = bx1 - 0.5f, c2 = bx2 - 0.5f;
        float xs = c1 + g * (c2 - c1);
        float x0f = fminf(fmaxf(floorf(xs), 0.0f), (float)(W-1));
        wx = fminf(fmaxf(xs - x0f, 0.0f), 1.0f);
        x0i = (int)x0f;
        x1i = min(x0i + 1, W - 1);

        float d1 = by1 - 0.5f, d2 = by2 - 0.5f;
        float ys = d1 + g * (d2 - d1);
        float y0f = fminf(fmaxf(floorf(ys), 0.0f), (float)(H-1));
        float wyv = fminf(fmaxf(ys - y0f, 0.0f), 1.0f);
        int y0 = (int)y0f;
        s_iy0[lane] = y0;
        s_iy1[lane] = min(y0 + 1, H - 1);
        s_wy[lane] = wyv;
    }
    __syncthreads();

    #pragma unroll
    for (int py = 0; py < ROI; py++) {
        float racc = 0.0f;
        #pragma unroll
        for (int sy = 0; sy < SR; sy++) {
            int yi = py * SR + sy;
            int y0 = s_iy0[yi], y1 = s_iy1[yi];   // LDS broadcast
            float wy = s_wy[yi];
            float v = 0.0f;
            if (lane < S_GRID) {
                const float* r0 = f + (size_t)y0 * W;
                const float* r1 = f + (size_t)y1 * W;
                float v00 = r0[x0i], v01 = r0[x1i];
                float v10 = r1[x0i], v11 = r1[x1i];
                float top = v00 + wx * (v01 - v00);
                float bot = v10 + wx * (v11 - v10);
                v = top + wy * (bot - top);
            }
            // segmented sum of groups of 6: valid at lanes 0,6,...,36
            float s = v;
            #pragma unroll
            for (int k = 1; k < 6; k++) s += __shfl_down(v, k);
            racc += s;
        }
        if (lane < S_GRID && (lane % 6) == 0)
            s_out[py * ROI + lane / 6] = racc;
    }
    __syncthreads();
    if (lane < 49)
        outp[(size_t)b * D_FEAT + c * 49 + lane] = s_out[lane];
}

// ---------------- K3: GEMM1 with fused A = (m0*img + m1*bev)*inv ----------------
#define GBM 64
#define GBN 64
#define GBK 16
__global__ __launch_bounds__(256) void gemm_fusedA_relu_kernel(
        const float* __restrict__ imgS, const float* __restrict__ bevS,
        const float* __restrict__ img_mask, const float* __restrict__ bev_mask,
        const float* __restrict__ B, const float* __restrict__ bias,
        float* __restrict__ C, int M, int N, int K) {
    __shared__ float As[GBK][GBM + 4];
    __shared__ float Bs[GBK][GBN];
    float m0 = img_mask[0], m1 = bev_mask[0];
    float inv = 1.0f / ((m0 + m1) * 36.0f);
    float w0 = m0 * inv, w1 = m1 * inv;
    int tid = threadIdx.x;
    int tx = tid & 15, ty = tid >> 4;
    int m0i = blockIdx.y * GBM, n0 = blockIdx.x * GBN;
    float acc[4][4] = {};
    int arow = tid >> 2;
    int acg  = (tid & 3) << 2;
    int brow = tid >> 4;
    int bcol = (tid & 15) << 2;

    for (int k0 = 0; k0 < K; k0 += GBK) {
        size_t aidx = (size_t)(m0i + arow) * K + k0 + acg;
        float4 ia = *(const float4*)(imgS + aidx);
        float4 ba = *(const float4*)(bevS + aidx);
        float4 av;
        av.x = w0 * ia.x + w1 * ba.x;
        av.y = w0 * ia.y + w1 * ba.y;
        av.z = w0 * ia.z + w1 * ba.z;
        av.w = w0 * ia.w + w1 * ba.w;
        float4 bv = *(const float4*)(B + (size_t)(k0 + brow) * N + n0 + bcol);
        __syncthreads();
        As[acg+0][arow] = av.x;
        As[acg+1][arow] = av.y;
        As[acg+2][arow] = av.z;
        As[acg+3][arow] = av.w;
        *(float4*)&Bs[brow][bcol] = bv;
        __syncthreads();
        #pragma unroll
        for (int kk = 0; kk < GBK; kk++) {
            float4 a = *(const float4*)&As[kk][ty * 4];
            float4 b = *(const float4*)&Bs[kk][tx * 4];
            float aa[4] = {a.x, a.y, a.z, a.w};
            float bb[4] = {b.x, b.y, b.z, b.w};
            #pragma unroll
            for (int i = 0; i < 4; i++)
                #pragma unroll
                for (int j = 0; j < 4; j++)
                    acc[i][j] += aa[i] * bb[j];
        }
    }
    float4 bv = *(const float4*)(bias + n0 + tx * 4);
    float bb[4] = {bv.x, bv.y, bv.z, bv.w};
    #pragma unroll
    for (int i = 0; i < 4; i++) {
        int m = m0i + ty * 4 + i;
        float4 o;
        o.x = fmaxf(acc[i][0] + bb[0], 0.0f);
        o.y = fmaxf(acc[i][1] + bb[1], 0.0f);
        o.z = fmaxf(acc[i][2] + bb[2], 0.0f);
        o.w = fmaxf(acc[i][3] + bb[3], 0.0f);
        *(float4*)(C + (size_t)m * N + n0 + tx * 4) = o;
    }
}

// ---------------- K4: plain fp32 tiled GEMM, C = relu(A@B + bias) ----------------
__global__ __launch_bounds__(256) void gemm_relu_kernel(
        const float* __restrict__ A, const float* __restrict__ B,
        const float* __restrict__ bias, float* __restrict__ C,
        int M, int N, int K, int do_relu) {
    __shared__ float As[GBK][GBM + 4];
    __shared__ float Bs[GBK][GBN];
    int tid = threadIdx.x;
    int tx = tid & 15, ty = tid >> 4;
    int m0 = blockIdx.y * GBM, n0 = blockIdx.x * GBN;
    float acc[4][4] = {};
    int arow = tid >> 2;
    int acg  = (tid & 3) << 2;
    int brow = tid >> 4;
    int bcol = (tid & 15) << 2;

    for (int k0 = 0; k0 < K; k0 += GBK) {
        float4 av = *(const float4*)(A + (size_t)(m0 + arow) * K + k0 + acg);
        float4 bv = *(const float4*)(B + (size_t)(k0 + brow) * N + n0 + bcol);
        __syncthreads();
        As[acg+0][arow] = av.x;
        As[acg+1][arow] = av.y;
        As[acg+2][arow] = av.z;
        As[acg+3][arow] = av.w;
        *(float4*)&Bs[brow][bcol] = bv;
        __syncthreads();
        #pragma unroll
        for (int kk = 0; kk < GBK; kk++) {
            float4 a = *(const float4*)&As[kk][ty * 4];
            float4 b = *(const float4*)&Bs[kk][tx * 4];
            float aa[4] = {a.x, a.y, a.z, a.w};
            float bb[4] = {b.x, b.y, b.z, b.w};
            #pragma unroll
            for (int i = 0; i < 4; i++)
                #pragma unroll
                for (int j = 0; j < 4; j++)
                    acc[i][j] += aa[i] * bb[j];
        }
    }
    float4 bv = *(const float4*)(bias + n0 + tx * 4);
    float bb[4] = {bv.x, bv.y, bv.z, bv.w};
    #pragma unroll
    for (int i = 0; i < 4; i++) {
        int m = m0 + ty * 4 + i;
        float4 o;
        float v0 = acc[i][0] + bb[0];
        float v1 = acc[i][1] + bb[1];
        float v2 = acc[i][2] + bb[2];
        float v3 = acc[i][3] + bb[3];
        if (do_relu) {
            v0 = fmaxf(v0, 0.0f); v1 = fmaxf(v1, 0.0f);
            v2 = fmaxf(v2, 0.0f); v3 = fmaxf(v3, 0.0f);
        }
        o.x = v0; o.y = v1; o.z = v2; o.w = v3;
        *(float4*)(C + (size_t)m * N + n0 + tx * 4) = o;
    }
}

// ---------------- K5: heads (obj/off/ang) + postprocess per row ----------------
__global__ __launch_bounds__(256) void heads_kernel(
        const float* __restrict__ h,
        const float* __restrict__ Wc, const float* __restrict__ bc,
        const float* __restrict__ Wo, const float* __restrict__ bo,
        const float* __restrict__ Wa, const float* __restrict__ ba,
        const float* __restrict__ anchors,
        float* __restrict__ obj_soft, float* __restrict__ off_out,
        float* __restrict__ orient, float* __restrict__ pred,
        float* __restrict__ pbev, float* __restrict__ scores) {
    int row = blockIdx.x;
    const float* hr = h + (size_t)row * HID;
    float acc[14];
    #pragma unroll
    for (int j = 0; j < 14; j++) acc[j] = 0.0f;
    for (int k = threadIdx.x; k < HID; k += 256) {
        float hv = hr[k];
        acc[0]  += hv * Wc[k*2+0];
        acc[1]  += hv * Wc[k*2+1];
        #pragma unroll
        for (int j = 0; j < 10; j++) acc[2+j] += hv * Wo[k*10+j];
        acc[12] += hv * Wa[k*2+0];
        acc[13] += hv * Wa[k*2+1];
    }
    #pragma unroll
    for (int d = 32; d > 0; d >>= 1) {
        #pragma unroll
        for (int j = 0; j < 14; j++) acc[j] += __shfl_down(acc[j], d);
    }
    __shared__ float red[4][14];
    int wid = threadIdx.x >> 6, lane = threadIdx.x & 63;
    if (lane == 0) {
        #pragma unroll
        for (int j = 0; j < 14; j++) red[wid][j] = acc[j];
    }
    __syncthreads();
    if (threadIdx.x == 0) {
        float f[14];
        #pragma unroll
        for (int j = 0; j < 14; j++)
            f[j] = red[0][j] + red[1][j] + red[2][j] + red[3][j];
        float obj0 = f[0] + bc[0], obj1 = f[1] + bc[1];
        float offv[10];
        #pragma unroll
        for (int j = 0; j < 10; j++) offv[j] = f[2+j] + bo[j];
        float ang0 = f[12] + ba[0], ang1 = f[13] + ba[1];
        float mx = fmaxf(obj0, obj1);
        float e0 = expf(obj0 - mx), e1 = expf(obj1 - mx);
        float den = e0 + e1;
        obj_soft[row*2+0] = e0 / den;
        obj_soft[row*2+1] = e1 / den;
        scores[row] = obj1;
        orient[row] = atan2f(ang1, ang0);
        float pa[6];
        #pragma unroll
        for (int j = 0; j < 6; j++) {
            pa[j] = anchors[row*6+j] + offv[j];
            pred[row*6+j] = pa[j];
        }
        #pragma unroll
        for (int j = 0; j < 10; j++) off_out[row*10+j] = offv[j];
        float x = pa[0], z = pa[2], ddx = pa[3], ddz = pa[5];
        pbev[row*4+0] = ((x - ddx*0.5f) - (-40.0f)) / 0.1f;
        pbev[row*4+1] = (70.0f - (z + ddz*0.5f)) / 0.1f;
        pbev[row*4+2] = ((x + ddx*0.5f) - (-40.0f)) / 0.1f;
        pbev[row*4+3] = (70.0f - (z - ddz*0.5f)) / 0.1f;
    }
}

// ---------------- K6: sequential NMS, single wave ----------------
__global__ void nms_kernel(const float* __restrict__ boxes,
                           const float* __restrict__ scores_g,
                           int* __restrict__ idx_out) {
    __shared__ float sb[N_PROP][4];
    __shared__ float sa[N_PROP];
    int lane = threadIdx.x;   // 64 threads
    float sc[16], x1[16], y1[16], x2[16], y2[16], ar[16];
    #pragma unroll
    for (int j = 0; j < 16; j++) {
        int g = lane + 64*j;
        float b0 = boxes[g*4+0], b1 = boxes[g*4+1];
        float b2 = boxes[g*4+2], b3 = boxes[g*4+3];
        x1[j] = b0; y1[j] = b1; x2[j] = b2; y2[j] = b3;
        ar[j] = (b2 - b0) * (b3 - b1);
        sc[j] = scores_g[g];
        sb[g][0] = b0; sb[g][1] = b1; sb[g][2] = b2; sb[g][3] = b3;
        sa[g] = ar[j];
    }
    for (int t = 0; t < NMS_K; t++) {
        float bv = -INFINITY;
        int bi = 0x7fffffff;
        #pragma unroll
        for (int j = 0; j < 16; j++) {
            int g = lane + 64*j;
            if (sc[j] > bv || (sc[j] == bv && g < bi)) { bv = sc[j]; bi = g; }
        }
        #pragma unroll
        for (int d = 1; d < 64; d <<= 1) {
            float ov = __shfl_xor(bv, d);
            int   oi = __shfl_xor(bi, d);
            if (ov > bv || (ov == bv && oi < bi)) { bv = ov; bi = oi; }
        }
        if (lane == 0) idx_out[t] = bi;
        float px1 = sb[bi][0], py1 = sb[bi][1], px2 = sb[bi][2], py2 = sb[bi][3];
        float pa = sa[bi];
        #pragma unroll
        for (int j = 0; j < 16; j++) {
            int g = lane + 64*j;
            float xx1 = fmaxf(x1[j], px1), yy1 = fmaxf(y1[j], py1);
            float xx2 = fminf(x2[j], px2), yy2 = fminf(y2[j], py2);
            float inter = fmaxf(xx2 - xx1, 0.0f) * fmaxf(yy2 - yy1, 0.0f);
            float iou = inter / (ar[j] + pa - inter + 1e-6f);
            if (iou > NMS_THR || g == bi) sc[j] = -INFINITY;
        }
    }
}

// ---------------- K7: gather outputs ----------------
__global__ void gather_kernel(const int* __restrict__ idx,
                              const float* __restrict__ obj_soft,
                              const float* __restrict__ pred,
                              const float* __restrict__ off,
                              const float* __restrict__ orient,
                              float* __restrict__ out) {
    int i = threadIdx.x;
    if (i < NMS_K) {
        int j = idx[i];
        out[2*i+0] = obj_soft[j*2+0];
        out[2*i+1] = obj_soft[j*2+1];
        #pragma unroll
        for (int t = 0; t < 6; t++) out[200 + 6*i + t] = pred[j*6+t];
        #pragma unroll
        for (int t = 0; t < 10; t++) out[800 + 10*i + t] = off[j*10+t];
        #pragma unroll
        for (int t = 0; t < 6; t++) out[1800 + 7*i + t] = pred[j*6+t];
        out[1800 + 7*i + 6] = 0.0f;
        out[2500 + i] = orient[j];
    }
}

extern "C" void kernel_launch(void* const* d_in, const int* in_sizes, int n_in,
                              void* d_out, int out_size, void* d_ws, size_t ws_size,
                              hipStream_t stream) {
    const float* imgF     = (const float*)d_in[0];
    const float* bevF     = (const float*)d_in[1];
    const float* anchors  = (const float*)d_in[2];
    const float* calib    = (const float*)d_in[3];
    const float* img_mask = (const float*)d_in[5];
    const float* bev_mask = (const float*)d_in[6];
    const float* W1 = (const float*)d_in[7];
    const float* b1 = (const float*)d_in[8];
    const float* W2 = (const float*)d_in[9];
    const float* b2 = (const float*)d_in[10];
    const float* Wc = (const float*)d_in[11];
    const float* bc = (const float*)d_in[12];
    const float* Wo = (const float*)d_in[13];
    const float* bo = (const float*)d_in[14];
    const float* Wa = (const float*)d_in[15];
    const float* ba = (const float*)d_in[16];
    const int* image_shape = (const int*)d_in[17];

    float* ws = (float*)d_ws;
    float* img_boxes = ws + WS_IMG_BOXES;
    float* bev_boxes = ws + WS_BEV_BOXES;
    float* img_s     = ws + WS_IMG_S;
    float* bev_s     = ws + WS_BEV_S;
    float* h1        = ws + WS_H1;
    float* h2        = ws + WS_H2;
    float* obj_soft  = ws + WS_OBJS;
    float* off       = ws + WS_OFF;
    float* orient    = ws + WS_ORIENT;
    float* pred      = ws + WS_PRED;
    float* pbev      = ws + WS_PBEV;
    float* scores    = ws + WS_SCORES;
    int*   idx       = (int*)(ws + WS_IDX);

    boxes_kernel<<<N_PROP/64, 64, 0, stream>>>(anchors, calib, image_shape,
                                               img_boxes, bev_boxes);
    roi_map_kernel<<<dim3(C_FEAT, N_PROP, 2), 64, 0, stream>>>(
        imgF, bevF, img_boxes, bev_boxes, img_s, bev_s);
    gemm_fusedA_relu_kernel<<<dim3(HID/GBN, N_PROP/GBM), 256, 0, stream>>>(
        img_s, bev_s, img_mask, bev_mask, W1, b1, h1, N_PROP, HID, D_FEAT);
    gemm_relu_kernel<<<dim3(HID/GBN, N_PROP/GBM), 256, 0, stream>>>(
        h1, W2, b2, h2, N_PROP, HID, HID, 1);
    heads_kernel<<<N_PROP, 256, 0, stream>>>(h2, Wc, bc, Wo, bo, Wa, ba, anchors,
                                             obj_soft, off, orient, pred, pbev, scores);
    nms_kernel<<<1, 64, 0, stream>>>(pbev, scores, idx);
    gather_kernel<<<1, 128, 0, stream>>>(idx, obj_soft, pred, off, orient,
                                         (float*)d_out);
}